// Round 15
// baseline (98.269 us; speedup 1.0000x reference)
//
#include <hip/hip_runtime.h>
#include <hip/hip_cooperative_groups.h>
#include <math.h>

namespace cg = cooperative_groups;

#define D 256
#define TWOD 512
#define BB 1024
#define NN 131072
#define LOG2E 1.4426950408889634f

typedef float v4f __attribute__((ext_vector_type(4)));

__device__ __forceinline__ v4f ldg_nt(const float* p, bool valid) {
  v4f z = {0.f, 0.f, 0.f, 0.f};
  if (valid) z = __builtin_nontemporal_load((const v4f*)p);
  return z;
}

__device__ __forceinline__ float dot4(v4f a, v4f b) {
  return fmaf(a.w, b.w, fmaf(a.z, b.z, fmaf(a.y, b.y, a.x * b.x)));
}

// Single cooperative kernel:
//   PRE-SYNC (per-block job by blk):
//     0..63   : Mt[d0+r][k] = sum_e Wq[e][d0+r]*Wk[e][k]      (4 rows)
//     64..127 : WfT[256+h0+j][d] = sum_v Wo[d][256+v]*Wv[v][h0+j]
//     128..143: WfT[k][d] = Wo[d][k]   (Wo_A transpose tiles)
//     144     : bqt[k] = sum_e Wk[e][k]*bq[e]
//     145     : cvec[d] = bo[d] + sum_v Wo[d][256+v]*bv[v]
//     146..255: offs scatter (grid-stride neighbor-diff)
//   grid.sync()
//   POST-SYNC: R13 f body (prologue GEMV + flash + merge + epilogue).
__global__ __launch_bounds__(1024) void fused_kernel(
    const float* __restrict__ H, const float* __restrict__ V,
    const int* __restrict__ bidx,
    const float* __restrict__ Wq, const float* __restrict__ bq,
    const float* __restrict__ Wk, const float* __restrict__ Wv,
    const float* __restrict__ bv, const float* __restrict__ Wo,
    const float* __restrict__ bo,
    float* __restrict__ Mt, float* __restrict__ WfT,
    float* __restrict__ bqt, float* __restrict__ cvec,
    int* __restrict__ offs, float* __restrict__ out) {
  __shared__ __align__(16) char smem[45056];
  // region A [0,32768): pre-sync job reduces / post-sync partq -> ss -> part
  // region B [32768,36864): Vs[4][256]
  // region C [36864,45056): Us2[512][4]
  float (*partq)[4][D] = (float(*)[4][D])smem;
  float (*ss)[D] = (float(*)[D])smem;
  float (*part)[4][D] = (float(*)[4][D])smem;
  float (*jp8)[4][D] = (float(*)[4][D])smem;      // Mt reduce [8][4][256]
  float (*jp4)[4][D] = (float(*)[4][D])smem;      // P reduce  [4][4][256]
  float (*tile)[65] = (float(*)[65])smem;         // transpose tile
  float* spart = (float*)smem;                    // [4][256] scalar-job reduce
  float* Vs  = (float*)(smem + 32768);
  float* Us2 = (float*)(smem + 36864);
  __shared__ float sm[16], sd[16];
  __shared__ int soff[5];

  const int t = threadIdx.x;
  const int wave = t >> 6, lane = t & 63;
  const int blk = blockIdx.x;
  const int b0 = blk * 4;

  // ---- stage V (region B; untouched by jobs)
  {
    const int i = t >> 8, d = t & 255;
    Vs[i * 256 + d] = V[(size_t)(b0 + i) * D + d];
  }

  // ================= PRE-SYNC JOBS =================
  if (blk < 64) {
    // Mt rows d0..d0+3 ; wave w covers e in [w*16,+16)
    const int d0 = blk * 4;
    const int k4 = lane * 4;
    v4f a0 = {0.f, 0.f, 0.f, 0.f}, a1 = a0, a2 = a0, a3 = a0;
    const int eb = wave * 16;
    #pragma unroll 4
    for (int ee = 0; ee < 16; ++ee) {
      const int e = eb + ee;
      const v4f wk4 = *(const v4f*)&Wk[(size_t)e * D + k4];  // coalesced
      const float* wqr = Wq + (size_t)e * D + d0;            // uniform
      a0 += wk4 * wqr[0];
      a1 += wk4 * wqr[1];
      a2 += wk4 * wqr[2];
      a3 += wk4 * wqr[3];
    }
    if (wave >= 8) {
      *(v4f*)&jp8[wave - 8][0][k4] = a0;
      *(v4f*)&jp8[wave - 8][1][k4] = a1;
      *(v4f*)&jp8[wave - 8][2][k4] = a2;
      *(v4f*)&jp8[wave - 8][3][k4] = a3;
    }
    __syncthreads();
    if (wave < 8) {
      v4f p0 = *(const v4f*)&jp8[wave][0][k4];
      v4f p1 = *(const v4f*)&jp8[wave][1][k4];
      v4f p2 = *(const v4f*)&jp8[wave][2][k4];
      v4f p3 = *(const v4f*)&jp8[wave][3][k4];
      *(v4f*)&jp8[wave][0][k4] = a0 + p0;
      *(v4f*)&jp8[wave][1][k4] = a1 + p1;
      *(v4f*)&jp8[wave][2][k4] = a2 + p2;
      *(v4f*)&jp8[wave][3][k4] = a3 + p3;
    }
    __syncthreads();
    {
      const int r = t >> 8, k = t & 255;
      float s = 0.f;
      #pragma unroll
      for (int w = 0; w < 8; ++w) s += jp8[w][r][k];
      Mt[(size_t)(d0 + r) * D + k] = s;
    }
  } else if (blk < 128) {
    // P rows h0..h0+3 ; thread (g = t>>8, d = t&255) covers v in [g*64,+64)
    const int h0 = (blk - 64) * 4;
    const int g = t >> 8, d = t & 255;
    float a0 = 0.f, a1 = 0.f, a2 = 0.f, a3 = 0.f;
    const int vb = g * 64;
    for (int vv = 0; vv < 64; ++vv) {
      const int v = vb + vv;
      const float wo = Wo[(size_t)d * TWOD + D + v];   // per-lane row walk (L1)
      const float* wvr = Wv + (size_t)v * D + h0;      // uniform
      a0 = fmaf(wvr[0], wo, a0);
      a1 = fmaf(wvr[1], wo, a1);
      a2 = fmaf(wvr[2], wo, a2);
      a3 = fmaf(wvr[3], wo, a3);
    }
    jp4[g][0][d] = a0; jp4[g][1][d] = a1; jp4[g][2][d] = a2; jp4[g][3][d] = a3;
    __syncthreads();
    {
      const int j = t >> 8, d2 = t & 255;
      const float s = jp4[0][j][d2] + jp4[1][j][d2] + jp4[2][j][d2] + jp4[3][j][d2];
      WfT[(size_t)(D + h0 + j) * D + d2] = s;
    }
  } else if (blk < 144) {
    // Wo_A transpose tile
    const int b = blk - 128;
    const int r0 = (b >> 2) * 64, c0 = (b & 3) * 64;
    const int tl = t & 63, rr = t >> 6;   // 16 rows per pass
    #pragma unroll
    for (int p = 0; p < 4; ++p) {
      const int r = p * 16 + rr;
      tile[r][tl] = Wo[(size_t)(r0 + r) * TWOD + c0 + tl];
    }
    __syncthreads();
    #pragma unroll
    for (int p = 0; p < 4; ++p) {
      const int r = p * 16 + rr;
      WfT[(size_t)(c0 + r) * D + r0 + tl] = tile[tl][r];
    }
  } else if (blk == 144) {
    // bqt
    const int g = t >> 8, k = t & 255;
    float a = 0.f;
    const int eb = g * 64;
    for (int ee = 0; ee < 64; ++ee) {
      const int e = eb + ee;
      a = fmaf(Wk[(size_t)e * D + k], bq[e], a);
    }
    spart[g * 256 + k] = a;
    __syncthreads();
    if (t < 256)
      bqt[t] = spart[0 * 256 + t] + spart[1 * 256 + t] +
               spart[2 * 256 + t] + spart[3 * 256 + t];
  } else if (blk == 145) {
    // cvec
    const int g = t >> 8, d = t & 255;
    float a = 0.f;
    const int vb = g * 64;
    for (int vv = 0; vv < 64; ++vv) {
      const int v = vb + vv;
      a = fmaf(Wo[(size_t)d * TWOD + D + v], bv[v], a);
    }
    spart[g * 256 + d] = a;
    __syncthreads();
    if (t < 256)
      cvec[t] = bo[t] + spart[0 * 256 + t] + spart[1 * 256 + t] +
                spart[2 * 256 + t] + spart[3 * 256 + t];
  } else {
    // offs scatter, grid-stride over blocks 146..255 (110 blocks x 1024 thr)
    const int idx = (blk - 146) * 1024 + t;
    for (int i = idx; i < NN; i += 110 * 1024) {
      const int b1 = bidx[i];
      const int b2 = (i + 1 < NN) ? bidx[i + 1] : BB;
      if (i == 0) {
        for (int b = 0; b <= b1; ++b) offs[b] = 0;
      }
      for (int b = b1 + 1; b <= b2; ++b) offs[b] = i + 1;
    }
  }

  // ================= GRID SYNC =================
  cg::this_grid().sync();

  // ================= POST-SYNC: R13 f body =================
  if (t < 5) soff[t] = offs[b0 + t];
  __syncthreads();

  const int ib = wave >> 2, ph = wave & 3;
  const int start = soff[ib];
  const int cnt = soff[ib + 1] - start;
  const int ck = (cnt + 3) >> 2;
  const int s0 = start + min(cnt, ph * ck);
  const int e0 = start + min(cnt, (ph + 1) * ck);
  int n = s0;
  v4f c0 = ldg_nt(H + (size_t)n * D + lane * 4, n < e0);
  v4f c1 = ldg_nt(H + (size_t)(n + 1) * D + lane * 4, n + 1 < e0);
  v4f f0 = ldg_nt(H + (size_t)(n + 2) * D + lane * 4, n + 2 < e0);
  v4f f1 = ldg_nt(H + (size_t)(n + 3) * D + lane * 4, n + 3 < e0);

  // ---- prologue: qt = Mt^T V + bqt ; wave covers d in [wave*16,+16)
  {
    v4f a0 = {0.f, 0.f, 0.f, 0.f}, a1 = a0, a2 = a0, a3 = a0;
    const int db = wave * 16;
    #pragma unroll 4
    for (int dd = 0; dd < 16; ++dd) {
      const int d = db + dd;
      const v4f w4 = *(const v4f*)(Mt + (size_t)d * D + lane * 4);
      a0 += w4 * Vs[0 * 256 + d];
      a1 += w4 * Vs[1 * 256 + d];
      a2 += w4 * Vs[2 * 256 + d];
      a3 += w4 * Vs[3 * 256 + d];
    }
    if (wave >= 8) {
      *(v4f*)&partq[wave - 8][0][lane * 4] = a0;
      *(v4f*)&partq[wave - 8][1][lane * 4] = a1;
      *(v4f*)&partq[wave - 8][2][lane * 4] = a2;
      *(v4f*)&partq[wave - 8][3][lane * 4] = a3;
    }
    __syncthreads();
    if (wave < 8) {
      v4f p0 = *(const v4f*)&partq[wave][0][lane * 4];
      v4f p1 = *(const v4f*)&partq[wave][1][lane * 4];
      v4f p2 = *(const v4f*)&partq[wave][2][lane * 4];
      v4f p3 = *(const v4f*)&partq[wave][3][lane * 4];
      *(v4f*)&partq[wave][0][lane * 4] = a0 + p0;
      *(v4f*)&partq[wave][1][lane * 4] = a1 + p1;
      *(v4f*)&partq[wave][2][lane * 4] = a2 + p2;
      *(v4f*)&partq[wave][3][lane * 4] = a3 + p3;
    }
  }
  __syncthreads();

  v4f q4 = *(const v4f*)(bqt + lane * 4);
  #pragma unroll
  for (int w = 0; w < 8; ++w) q4 += *(const v4f*)&partq[w][ib][lane * 4];
  __syncthreads();   // partq dead; ss region may now be written

  // ---- flash over contiguous chunk [s0,e0)
  float m = -1e30f, den = 0.f;
  v4f acc = {0.f, 0.f, 0.f, 0.f};
  {
    const float SC = 0.0625f * LOG2E;
    const int odd = lane & 1;
    while (n < e0) {
      const int nn = n + 4;
      v4f g0 = ldg_nt(H + (size_t)nn * D + lane * 4, nn < e0);
      v4f g1 = ldg_nt(H + (size_t)(nn + 1) * D + lane * 4, nn + 1 < e0);

      const float d0 = dot4(c0, q4);
      const float d1 = dot4(c1, q4);
      const float mine = odd ? d1 : d0;
      const float oth  = odd ? d0 : d1;
      float s = mine + __shfl_xor(oth, 1);
      s += __shfl_xor(s, 2);
      s += __shfl_xor(s, 4);
      s += __shfl_xor(s, 8);
      s += __shfl_xor(s, 16);
      s += __shfl_xor(s, 32);
      const float sc = (n + odd < e0) ? s * SC : -1e30f;

      const float mm = fmaxf(sc, __shfl_xor(sc, 1));
      const float nm = fmaxf(m, mm);
      const float f = exp2f(m - nm);
      const float w = exp2f(sc - nm);
      const float wx = __shfl_xor(w, 1);
      const float wr0 = odd ? wx : w;
      const float wr1 = odd ? w : wx;
      den = fmaf(den, f, w + wx);
      acc = acc * f + c0 * wr0 + c1 * wr1;
      m = nm;

      c0 = f0; c1 = f1; f0 = g0; f1 = g1; n += 2;
    }
  }
  *(v4f*)&ss[wave][lane * 4] = acc;
  if (lane == 0) { sm[wave] = m; sd[wave] = den; }
  __syncthreads();

  // ---- merge 4 waves per batch -> Us2 = [V ; s_norm]
  {
    const int i = t >> 8, d = t & 255;
    const int w0 = i * 4;
    const float m0 = sm[w0], m1 = sm[w0 + 1], m2 = sm[w0 + 2], m3 = sm[w0 + 3];
    const float M = fmaxf(fmaxf(m0, m1), fmaxf(m2, m3));
    const float f0m = exp2f(m0 - M), f1m = exp2f(m1 - M);
    const float f2m = exp2f(m2 - M), f3m = exp2f(m3 - M);
    const float Dn = sd[w0] * f0m + sd[w0 + 1] * f1m + sd[w0 + 2] * f2m + sd[w0 + 3] * f3m;
    const float inv = (Dn > 0.f) ? (1.f / Dn) : 0.f;
    const float sv = (ss[w0][d] * f0m + ss[w0 + 1][d] * f1m +
                      ss[w0 + 2][d] * f2m + ss[w0 + 3][d] * f3m) * inv;
    Us2[d * 4 + i] = Vs[i * 256 + d];
    Us2[(D + d) * 4 + i] = sv;
  }
  __syncthreads();

  // ---- epilogue: out = WfT^T Us2 + cvec ; wave covers k in [wave*32,+32)
  {
    v4f a0 = {0.f, 0.f, 0.f, 0.f}, a1 = a0, a2 = a0, a3 = a0;
    const int kb = wave * 32;
    #pragma unroll 4
    for (int kk = 0; kk < 32; ++kk) {
      const int k = kb + kk;
      const v4f w4 = *(const v4f*)(WfT + (size_t)k * D + lane * 4);
      const v4f u4 = *(const v4f*)&Us2[k * 4];
      a0 += w4 * u4.x; a1 += w4 * u4.y; a2 += w4 * u4.z; a3 += w4 * u4.w;
    }
    if (wave >= 8) {
      *(v4f*)&part[wave - 8][0][lane * 4] = a0;
      *(v4f*)&part[wave - 8][1][lane * 4] = a1;
      *(v4f*)&part[wave - 8][2][lane * 4] = a2;
      *(v4f*)&part[wave - 8][3][lane * 4] = a3;
    }
    __syncthreads();
    if (wave < 8) {
      v4f p0 = *(const v4f*)&part[wave][0][lane * 4];
      v4f p1 = *(const v4f*)&part[wave][1][lane * 4];
      v4f p2 = *(const v4f*)&part[wave][2][lane * 4];
      v4f p3 = *(const v4f*)&part[wave][3][lane * 4];
      *(v4f*)&part[wave][0][lane * 4] = a0 + p0;
      *(v4f*)&part[wave][1][lane * 4] = a1 + p1;
      *(v4f*)&part[wave][2][lane * 4] = a2 + p2;
      *(v4f*)&part[wave][3][lane * 4] = a3 + p3;
    }
  }
  __syncthreads();
  {
    const int i = t >> 8, d = t & 255;
    const int bb2 = b0 + i;
    float s = cvec[d];
    #pragma unroll
    for (int w = 0; w < 8; ++w) s += part[w][i][d];
    const int c = soff[i + 1] - soff[i];
    out[(size_t)bb2 * D + d] = (c > 0) ? s : Us2[d * 4 + i];
  }
}

extern "C" void kernel_launch(void* const* d_in, const int* in_sizes, int n_in,
                              void* d_out, int out_size, void* d_ws, size_t ws_size,
                              hipStream_t stream) {
  const float* V   = (const float*)d_in[0];
  const float* H   = (const float*)d_in[1];
  const int* bidx  = (const int*)d_in[2];
  const float* Wq  = (const float*)d_in[3];
  const float* bq  = (const float*)d_in[4];
  const float* Wk  = (const float*)d_in[5];
  const float* Wv  = (const float*)d_in[7];
  const float* bv  = (const float*)d_in[8];
  const float* Wo  = (const float*)d_in[9];
  const float* bo  = (const float*)d_in[10];
  float* out = (float*)d_out;

  float* ws  = (float*)d_ws;
  float* Mt  = ws;                       // 256*256
  float* WfT = Mt + D * D;               // 512*256
  float* bqt = WfT + TWOD * D;           // 256
  float* cv  = bqt + D;                  // 256
  int* offs  = (int*)(cv + D);           // 1025

  void* args[] = {
      (void*)&H, (void*)&V, (void*)&bidx, (void*)&Wq, (void*)&bq,
      (void*)&Wk, (void*)&Wv, (void*)&bv, (void*)&Wo, (void*)&bo,
      (void*)&Mt, (void*)&WfT, (void*)&bqt, (void*)&cv, (void*)&offs,
      (void*)&out};
  hipLaunchCooperativeKernel((const void*)fused_kernel, dim3(256), dim3(1024),
                             args, 0, stream);
}

// Round 16
// 54.072 us; speedup vs baseline: 1.8174x; 1.8174x over previous
//
#include <hip/hip_runtime.h>
#include <math.h>

#define D 256
#define TWOD 512
#define BB 1024
#define NN 131072
#define LOG2E 1.4426950408889634f

typedef float v4f __attribute__((ext_vector_type(4)));

__device__ __forceinline__ v4f ldg_nt(const float* p, bool valid) {
  v4f z = {0.f, 0.f, 0.f, 0.f};
  if (valid) z = __builtin_nontemporal_load((const v4f*)p);
  return z;
}

__device__ __forceinline__ float dot4(v4f a, v4f b) {
  return fmaf(a.w, b.w, fmaf(a.z, b.z, fmaf(a.y, b.y, a.x * b.x)));
}

// butterfly pack: lane with rot r ends with full sum of row (base + r)
__device__ __forceinline__ float pack4(float d0, float d1, float d2, float d3) {
  float a01 = d0 + __shfl_xor(d1, 4);
  float a23 = d2 + __shfl_xor(d3, 4);
  float s = a01 + __shfl_xor(a23, 8);
  s += __shfl_xor(s, 1);
  s += __shfl_xor(s, 2);
  s += __shfl_xor(s, 16);
  s += __shfl_xor(s, 32);
  return s;
}

// ---------------- prep:
// blocks 0..255   : qt[b] = Wk^T (Wq V[b] + bq)   (R5-proven 2-stage butterfly, 4 b/block)
// blocks 256..319 : WfT[256+h][d] = (Wo_B @ Wv)[d][h]   (4 h/block)
// blocks 320..335 : WfT[k][d] = Wo[d][k]          (Wo_A transpose tiles)
// block 336       : cvec[d] = bo[d] + sum_v Wo[d][256+v]*bv[v]
// blocks 337..848 : offs scatter
__global__ __launch_bounds__(256) void prep_kernel(
    const float* __restrict__ V, const float* __restrict__ Wq,
    const float* __restrict__ bq, const float* __restrict__ Wk,
    const float* __restrict__ Wv, const float* __restrict__ bv,
    const float* __restrict__ Wo, const float* __restrict__ bo,
    const int* __restrict__ bidx,
    float* __restrict__ qt, float* __restrict__ WfT,
    float* __restrict__ cvec, int* __restrict__ offs) {
  __shared__ __align__(16) char smem[24576];
  const int blk = blockIdx.x;
  const int t = threadIdx.x;

  if (blk < 256) {
    // ---- kq: qt[b] = Wk^T (Wq V[b] + bq), 4 batches/block (R5-proven)
    float* Vs   = (float*)smem;            // [4][256]
    float* q1s4 = (float*)(smem + 4096);   // [256][4]
    float* part = (float*)(smem + 8192);   // [4 waves][4 batches][256]
    const int wq = t >> 6, lane = t & 63;
    const int b0 = blk * 4;
    for (int i = 0; i < 4; ++i) Vs[i * 256 + t] = V[(size_t)(b0 + i) * D + t];
    __syncthreads();
    const int rot = (lane >> 2) & 3;
    const v4f vb0 = *(const v4f*)&Vs[0 * 256 + lane * 4];
    const v4f vb1 = *(const v4f*)&Vs[1 * 256 + lane * 4];
    const v4f vb2 = *(const v4f*)&Vs[2 * 256 + lane * 4];
    const v4f vb3 = *(const v4f*)&Vs[3 * 256 + lane * 4];

    // stage 1: q1 = Wq V (rotated rows, butterfly reduce)
    for (int ii = 0; ii < 16; ++ii) {
      const int cb = wq * 64 + ii * 4;
      const v4f r0 = *(const v4f*)(Wq + (size_t)(cb + (rot ^ 0)) * D + lane * 4);
      const v4f r1 = *(const v4f*)(Wq + (size_t)(cb + (rot ^ 1)) * D + lane * 4);
      const v4f r2 = *(const v4f*)(Wq + (size_t)(cb + (rot ^ 2)) * D + lane * 4);
      const v4f r3 = *(const v4f*)(Wq + (size_t)(cb + (rot ^ 3)) * D + lane * 4);
      const float s0 = pack4(dot4(r0, vb0), dot4(r1, vb0), dot4(r2, vb0), dot4(r3, vb0));
      const float s1 = pack4(dot4(r0, vb1), dot4(r1, vb1), dot4(r2, vb1), dot4(r3, vb1));
      const float s2 = pack4(dot4(r0, vb2), dot4(r1, vb2), dot4(r2, vb2), dot4(r3, vb2));
      const float s3 = pack4(dot4(r0, vb3), dot4(r1, vb3), dot4(r2, vb3), dot4(r3, vb3));
      if (lane < 16 && (lane & 3) == 0) {
        v4f o = {s0, s1, s2, s3};
        *(v4f*)&q1s4[(cb + rot) * 4] = o;
      }
    }
    __syncthreads();

    // stage 2: qt = Wk^T (q1 + bq), wave covers k in [wq*64,+64)
    v4f a0 = {0.f, 0.f, 0.f, 0.f}, a1 = a0, a2 = a0, a3 = a0;
    const int kb = wq * 64;
    for (int kk = 0; kk < 64; ++kk) {
      const int k = kb + kk;
      const v4f w4 = *(const v4f*)(Wk + (size_t)k * D + lane * 4);
      const v4f q = *(const v4f*)&q1s4[k * 4];
      const float bqk = bq[k];
      a0 += w4 * (q.x + bqk);
      a1 += w4 * (q.y + bqk);
      a2 += w4 * (q.z + bqk);
      a3 += w4 * (q.w + bqk);
    }
    *(v4f*)&part[(wq * 4 + 0) * 256 + lane * 4] = a0;
    *(v4f*)&part[(wq * 4 + 1) * 256 + lane * 4] = a1;
    *(v4f*)&part[(wq * 4 + 2) * 256 + lane * 4] = a2;
    *(v4f*)&part[(wq * 4 + 3) * 256 + lane * 4] = a3;
    __syncthreads();
    #pragma unroll
    for (int b = 0; b < 4; ++b) {
      const float s = part[(0 * 4 + b) * 256 + t] + part[(1 * 4 + b) * 256 + t] +
                      part[(2 * 4 + b) * 256 + t] + part[(3 * 4 + b) * 256 + t];
      qt[(size_t)(b0 + b) * D + t] = s;
    }
  } else if (blk < 320) {
    // ---- P = Wo_B @ Wv rows -> WfT[256+h][d]
    const int h0 = (blk - 256) * 4;
    float a0 = 0.f, a1 = 0.f, a2 = 0.f, a3 = 0.f;
    for (int v = 0; v < D; ++v) {
      const float wo = Wo[(size_t)t * TWOD + D + v]; // per-lane own-row walk (L1)
      const float* wvr = Wv + (size_t)v * D + h0;    // uniform -> sgpr
      a0 = fmaf(wvr[0], wo, a0);
      a1 = fmaf(wvr[1], wo, a1);
      a2 = fmaf(wvr[2], wo, a2);
      a3 = fmaf(wvr[3], wo, a3);
    }
    WfT[(size_t)(D + h0 + 0) * D + t] = a0;
    WfT[(size_t)(D + h0 + 1) * D + t] = a1;
    WfT[(size_t)(D + h0 + 2) * D + t] = a2;
    WfT[(size_t)(D + h0 + 3) * D + t] = a3;
  } else if (blk < 336) {
    // ---- Wo_A transpose tiles
    float (*tile)[65] = (float(*)[65])smem;
    const int b = blk - 320;
    const int r0 = (b >> 2) * 64, c0 = (b & 3) * 64;
    const int lane = t & 63, sr = t >> 6;
    #pragma unroll 4
    for (int rr = 0; rr < 16; ++rr) {
      const int r = rr * 4 + sr;
      tile[r][lane] = Wo[(size_t)(r0 + r) * TWOD + c0 + lane];
    }
    __syncthreads();
    #pragma unroll 4
    for (int rr = 0; rr < 16; ++rr) {
      const int r = rr * 4 + sr;
      WfT[(size_t)(c0 + r) * D + r0 + lane] = tile[lane][r];
    }
  } else if (blk == 336) {
    float a = bo[t];
    for (int v = 0; v < D; ++v)
      a = fmaf(Wo[(size_t)t * TWOD + D + v], bv[v], a);
    cvec[t] = a;
  } else {
    const int i = (blk - 337) * 256 + t;
    if (i >= NN) return;
    const int b1 = bidx[i];
    const int b2 = (i + 1 < NN) ? bidx[i + 1] : BB;
    if (i == 0) {
      for (int b = 0; b <= b1; ++b) offs[b] = 0;
    }
    for (int b = b1 + 1; b <= b2; ++b) offs[b] = i + 1;
  }
}

// ---------------- f: flash + merge + epilogue (NO prologue; q4 read from prep's qt)
// 256 blocks x 1024 threads, 4 batches/block, 4 waves/batch, contiguous chunks.
__global__ __launch_bounds__(1024) void f_kernel(
    const float* __restrict__ H, const float* __restrict__ V,
    const float* __restrict__ qt, const int* __restrict__ offs,
    const float* __restrict__ WfT, const float* __restrict__ cvec,
    float* __restrict__ out) {
  __shared__ __align__(16) char smem[40960];
  // region A [0,32768): flash ss[16][256] -> epi part[8][4][256]
  // region B [32768,40960): Us2[512][4]  (V staged into rows 0..255 at start)
  float (*ss)[D] = (float(*)[D])smem;
  float (*part)[4][D] = (float(*)[4][D])smem;
  float* Us2 = (float*)(smem + 32768);
  __shared__ float sm[16], sd[16];
  __shared__ int soff[5];

  const int t = threadIdx.x;
  const int wave = t >> 6, lane = t & 63;
  const int blk = blockIdx.x;
  const int b0 = blk * 4;

  if (t < 5) soff[t] = offs[b0 + t];
  {
    const int i = t >> 8, d = t & 255;
    Us2[d * 4 + i] = V[(size_t)(b0 + i) * D + d];
  }
  __syncthreads();

  const int ib = wave >> 2, ph = wave & 3;
  const int bb = b0 + ib;
  const int start = soff[ib];
  const int cnt = soff[ib + 1] - start;
  const int ck = (cnt + 3) >> 2;
  const int s0 = start + min(cnt, ph * ck);
  const int e0 = start + min(cnt, (ph + 1) * ck);

  // q4 from prep's qt (L2); issued together with first H loads
  const v4f q4 = *(const v4f*)(qt + (size_t)bb * D + lane * 4);
  int n = s0;
  v4f c0 = ldg_nt(H + (size_t)n * D + lane * 4, n < e0);
  v4f c1 = ldg_nt(H + (size_t)(n + 1) * D + lane * 4, n + 1 < e0);
  v4f f0 = ldg_nt(H + (size_t)(n + 2) * D + lane * 4, n + 2 < e0);
  v4f f1 = ldg_nt(H + (size_t)(n + 3) * D + lane * 4, n + 3 < e0);

  // ---- flash over contiguous chunk [s0,e0), 2 rows/iter, depth-2 prefetch
  float m = -1e30f, den = 0.f;
  v4f acc = {0.f, 0.f, 0.f, 0.f};
  {
    const float SC = 0.0625f * LOG2E;
    const int odd = lane & 1;
    while (n < e0) {
      const int nn = n + 4;
      v4f g0 = ldg_nt(H + (size_t)nn * D + lane * 4, nn < e0);
      v4f g1 = ldg_nt(H + (size_t)(nn + 1) * D + lane * 4, nn + 1 < e0);

      const float d0 = dot4(c0, q4);
      const float d1 = dot4(c1, q4);
      const float mine = odd ? d1 : d0;
      const float oth  = odd ? d0 : d1;
      float s = mine + __shfl_xor(oth, 1);
      s += __shfl_xor(s, 2);
      s += __shfl_xor(s, 4);
      s += __shfl_xor(s, 8);
      s += __shfl_xor(s, 16);
      s += __shfl_xor(s, 32);
      const float sc = (n + odd < e0) ? s * SC : -1e30f;

      const float mm = fmaxf(sc, __shfl_xor(sc, 1));
      const float nm = fmaxf(m, mm);
      const float f = exp2f(m - nm);
      const float w = exp2f(sc - nm);
      const float wx = __shfl_xor(w, 1);
      const float wr0 = odd ? wx : w;
      const float wr1 = odd ? w : wx;
      den = fmaf(den, f, w + wx);
      acc = acc * f + c0 * wr0 + c1 * wr1;
      m = nm;

      c0 = f0; c1 = f1; f0 = g0; f1 = g1; n += 2;
    }
  }
  *(v4f*)&ss[wave][lane * 4] = acc;
  if (lane == 0) { sm[wave] = m; sd[wave] = den; }
  __syncthreads();

  // ---- merge 4 waves per batch -> Us2 upper half
  {
    const int i = t >> 8, d = t & 255;
    const int w0 = i * 4;
    const float m0 = sm[w0], m1 = sm[w0 + 1], m2 = sm[w0 + 2], m3 = sm[w0 + 3];
    const float M = fmaxf(fmaxf(m0, m1), fmaxf(m2, m3));
    const float f0m = exp2f(m0 - M), f1m = exp2f(m1 - M);
    const float f2m = exp2f(m2 - M), f3m = exp2f(m3 - M);
    const float Dn = sd[w0] * f0m + sd[w0 + 1] * f1m + sd[w0 + 2] * f2m + sd[w0 + 3] * f3m;
    const float inv = (Dn > 0.f) ? (1.f / Dn) : 0.f;
    const float sv = (ss[w0][d] * f0m + ss[w0 + 1][d] * f1m +
                      ss[w0 + 2][d] * f2m + ss[w0 + 3][d] * f3m) * inv;
    __syncthreads();              // all ss reads done before part overwrites
    Us2[(D + d) * 4 + i] = sv;
  }
  __syncthreads();

  // ---- epilogue: out = WfT^T Us2 + cvec ; wave covers k in [wave*32,+32) of K=512
  {
    v4f a0 = {0.f, 0.f, 0.f, 0.f}, a1 = a0, a2 = a0, a3 = a0;
    const int kb = wave * 32;
    #pragma unroll 4
    for (int kk = 0; kk < 32; ++kk) {
      const int k = kb + kk;
      const v4f w4 = *(const v4f*)(WfT + (size_t)k * D + lane * 4);
      const v4f u4 = *(const v4f*)&Us2[k * 4];     // b128 broadcast
      a0 += w4 * u4.x; a1 += w4 * u4.y; a2 += w4 * u4.z; a3 += w4 * u4.w;
    }
    if (wave >= 8) {
      *(v4f*)&part[wave - 8][0][lane * 4] = a0;
      *(v4f*)&part[wave - 8][1][lane * 4] = a1;
      *(v4f*)&part[wave - 8][2][lane * 4] = a2;
      *(v4f*)&part[wave - 8][3][lane * 4] = a3;
    }
    __syncthreads();
    if (wave < 8) {
      v4f p0 = *(const v4f*)&part[wave][0][lane * 4];
      v4f p1 = *(const v4f*)&part[wave][1][lane * 4];
      v4f p2 = *(const v4f*)&part[wave][2][lane * 4];
      v4f p3 = *(const v4f*)&part[wave][3][lane * 4];
      *(v4f*)&part[wave][0][lane * 4] = a0 + p0;
      *(v4f*)&part[wave][1][lane * 4] = a1 + p1;
      *(v4f*)&part[wave][2][lane * 4] = a2 + p2;
      *(v4f*)&part[wave][3][lane * 4] = a3 + p3;
    }
  }
  __syncthreads();
  {
    const int i = t >> 8, d = t & 255;
    const int bb2 = b0 + i;
    float s = cvec[d];
    #pragma unroll
    for (int w = 0; w < 8; ++w) s += part[w][i][d];
    const int c = soff[i + 1] - soff[i];
    out[(size_t)bb2 * D + d] = (c > 0) ? s : Us2[d * 4 + i];
  }
}

extern "C" void kernel_launch(void* const* d_in, const int* in_sizes, int n_in,
                              void* d_out, int out_size, void* d_ws, size_t ws_size,
                              hipStream_t stream) {
  const float* V   = (const float*)d_in[0];
  const float* H   = (const float*)d_in[1];
  const int* bidx  = (const int*)d_in[2];
  const float* Wq  = (const float*)d_in[3];
  const float* bq  = (const float*)d_in[4];
  const float* Wk  = (const float*)d_in[5];
  const float* Wv  = (const float*)d_in[7];
  const float* bv  = (const float*)d_in[8];
  const float* Wo  = (const float*)d_in[9];
  const float* bo  = (const float*)d_in[10];
  float* out = (float*)d_out;

  float* ws  = (float*)d_ws;
  float* qtb = ws;                       // 1024*256
  float* WfT = qtb + BB * D;             // 512*256
  float* cv  = WfT + TWOD * D;           // 256
  int* offs  = (int*)(cv + D);           // 1025

  hipLaunchKernelGGL(prep_kernel, dim3(849), dim3(256), 0, stream,
                     V, Wq, bq, Wk, Wv, bv, Wo, bo, bidx,
                     qtb, WfT, cv, offs);
  hipLaunchKernelGGL(f_kernel, dim3(BB / 4), dim3(1024), 0, stream,
                     H, V, qtb, offs, WfT, cv, out);
}